// Round 1
// baseline (606.044 us; speedup 1.0000x reference)
//
#include <hip/hip_runtime.h>
#include <hip/hip_bf16.h>

// LSTMFeatureExtractor: 2-layer LSTM (H=64, IN=1, B=2048, T=512) + FC(64->32)+ReLU
// Strategy: persistent per-block recurrence, f16 MFMA 16x16x32 for the three
// recurrent matmuls (fp32 accumulate), fp32 cell math, weights in VGPRs.
// 256 blocks x 256 threads; M=8 real batches/block (MFMA rows 8-15 mirror 0-7).

#define HID 64
#define TSTEPS 512
#define MB 8
#define ROWSTRIDE 72  // fp16 elems per h-row in LDS: 144B -> 2-way bank alias (free)

typedef _Float16 f16x8 __attribute__((ext_vector_type(8)));
typedef float f32x4 __attribute__((ext_vector_type(4)));

__device__ __forceinline__ float fast_sigmoid(float x) {
    // 1 / (1 + 2^(-x*log2e))
    float e = __builtin_amdgcn_exp2f(-1.44269504089f * x);
    return __builtin_amdgcn_rcpf(1.0f + e);
}
__device__ __forceinline__ float fast_tanh(float x) {
    // 1 - 2/(1 + 2^(2x*log2e)); correct limits at +/-inf (rcp(inf)=0)
    float e = __builtin_amdgcn_exp2f(2.88539008178f * x);
    return 1.0f - 2.0f * __builtin_amdgcn_rcpf(1.0f + e);
}

__global__ __launch_bounds__(256, 1) void lstm_feat_kernel(
    const float* __restrict__ x,
    const float* __restrict__ Wih0, const float* __restrict__ Whh0,
    const float* __restrict__ bih0, const float* __restrict__ bhh0,
    const float* __restrict__ Wih1, const float* __restrict__ Whh1,
    const float* __restrict__ bih1, const float* __restrict__ bhh1,
    const float* __restrict__ fcW, const float* __restrict__ fcb,
    float* __restrict__ out)
{
    __shared__ float x_lds[TSTEPS * MB];                       // 16 KB, [t][r]
    __shared__ __align__(16) _Float16 h0_lds[2][16 * ROWSTRIDE];
    __shared__ __align__(16) _Float16 h1_lds[2][16 * ROWSTRIDE];
    __shared__ float h1f32[MB * HID];                          // final h for fc
    __shared__ float fcw_lds[32 * HID];                        // 8 KB
    __shared__ float fcb_lds[32];

    const int tid  = threadIdx.x;
    const int wave = tid >> 6;      // 0..3: owns units [16w, 16w+16) for all gates
    const int lane = tid & 63;
    const int nq   = lane & 15;     // n within tile (B/D); m (batch row) for A
    const int quad = lane >> 4;     // k-block selector for A/B; row-group for C/D
    const int bbase = blockIdx.x * MB;

    // ---- one-time staging ----
    for (int i = tid; i < TSTEPS * MB; i += 256) {
        int r = i >> 9, t = i & (TSTEPS - 1);
        x_lds[t * MB + r] = x[(bbase + r) * TSTEPS + t];   // coalesced in t
    }
    for (int i = tid; i < 32 * HID; i += 256) fcw_lds[i] = fcW[i];
    if (tid < 32) fcb_lds[tid] = fcb[tid];
    for (int i = tid; i < 16 * ROWSTRIDE; i += 256) {
        h0_lds[0][i] = (_Float16)0.f;
        h1_lds[0][i] = (_Float16)0.f;
    }

    // ---- per-lane weight fragments (B operand: lane holds W[n][k..k+8)) ----
    const int u = wave * 16 + nq;   // unit owned: 0..63
    f16x8 w0[4][2], wi1[4][2], wh1[4][2];
    float b0v[4], b1v[4], wx0[4];
    #pragma unroll
    for (int g = 0; g < 4; ++g) {
        const int n = g * 64 + u;
        b0v[g] = bih0[n] + bhh0[n];
        b1v[g] = bih1[n] + bhh1[n];
        wx0[g] = Wih0[n];           // IN==1
        #pragma unroll
        for (int ks = 0; ks < 2; ++ks) {
            const int k0 = quad * 8 + ks * 32;
            f16x8 a, b, c;
            #pragma unroll
            for (int j = 0; j < 8; ++j) {
                a[j] = (_Float16)Whh0[n * HID + k0 + j];
                b[j] = (_Float16)Wih1[n * HID + k0 + j];
                c[j] = (_Float16)Whh1[n * HID + k0 + j];
            }
            w0[g][ks] = a; wi1[g][ks] = b; wh1[g][ks] = c;
        }
    }

    float c0[4] = {0.f, 0.f, 0.f, 0.f};
    float c1[4] = {0.f, 0.f, 0.f, 0.f};
    float h1last[4] = {0.f, 0.f, 0.f, 0.f};

    __syncthreads();

    int p = 0;
    for (int t = 0; t < TSTEPS; ++t) {
        const int q = p ^ 1;

        // A-fragments of h0_prev / h1_prev: lane m=nq, k = quad*8 + ks*32
        f16x8 a0[2], a1[2];
        #pragma unroll
        for (int ks = 0; ks < 2; ++ks) {
            a0[ks] = *(const f16x8*)&h0_lds[p][nq * ROWSTRIDE + quad * 8 + ks * 32];
            a1[ks] = *(const f16x8*)&h1_lds[p][nq * ROWSTRIDE + quad * 8 + ks * 32];
        }
        float xr[4];
        #pragma unroll
        for (int r = 0; r < 4; ++r) {
            const int row = (quad * 4 + r) & (MB - 1);  // rows 8-15 mirror 0-7
            xr[r] = x_lds[t * MB + row];
        }

        // ---- layer 0: gates = x*Wih0 + b0 + h0_prev @ Whh0^T ----
        f32x4 acc[4];
        #pragma unroll
        for (int g = 0; g < 4; ++g) {
            #pragma unroll
            for (int r = 0; r < 4; ++r) acc[g][r] = b0v[g] + xr[r] * wx0[g];
            acc[g] = __builtin_amdgcn_mfma_f32_16x16x32_f16(a0[0], w0[g][0], acc[g], 0, 0, 0);
            acc[g] = __builtin_amdgcn_mfma_f32_16x16x32_f16(a0[1], w0[g][1], acc[g], 0, 0, 0);
        }
        // cell0 (lane-local; D layout: col=nq -> unit u, row=quad*4+r)
        #pragma unroll
        for (int r = 0; r < 4; ++r) {
            const float iv = fast_sigmoid(acc[0][r]);
            const float fv = fast_sigmoid(acc[1][r]);
            const float gv = fast_tanh(acc[2][r]);
            const float ov = fast_sigmoid(acc[3][r]);
            const float c = fv * c0[r] + iv * gv;
            c0[r] = c;
            const float h = ov * fast_tanh(c);
            h0_lds[q][(quad * 4 + r) * ROWSTRIDE + u] = (_Float16)h;
        }
        __syncthreads();   // h0_new visible to all waves

        // ---- layer 1: gates = b1 + h0_new @ Wih1^T + h1_prev @ Whh1^T ----
        f16x8 a0n[2];
        a0n[0] = *(const f16x8*)&h0_lds[q][nq * ROWSTRIDE + quad * 8];
        a0n[1] = *(const f16x8*)&h0_lds[q][nq * ROWSTRIDE + quad * 8 + 32];
        #pragma unroll
        for (int g = 0; g < 4; ++g) {
            #pragma unroll
            for (int r = 0; r < 4; ++r) acc[g][r] = b1v[g];
            acc[g] = __builtin_amdgcn_mfma_f32_16x16x32_f16(a0n[0], wi1[g][0], acc[g], 0, 0, 0);
            acc[g] = __builtin_amdgcn_mfma_f32_16x16x32_f16(a0n[1], wi1[g][1], acc[g], 0, 0, 0);
            acc[g] = __builtin_amdgcn_mfma_f32_16x16x32_f16(a1[0],  wh1[g][0], acc[g], 0, 0, 0);
            acc[g] = __builtin_amdgcn_mfma_f32_16x16x32_f16(a1[1],  wh1[g][1], acc[g], 0, 0, 0);
        }
        #pragma unroll
        for (int r = 0; r < 4; ++r) {
            const float iv = fast_sigmoid(acc[0][r]);
            const float fv = fast_sigmoid(acc[1][r]);
            const float gv = fast_tanh(acc[2][r]);
            const float ov = fast_sigmoid(acc[3][r]);
            const float c = fv * c1[r] + iv * gv;
            c1[r] = c;
            const float h = ov * fast_tanh(c);
            h1last[r] = h;
            h1_lds[q][(quad * 4 + r) * ROWSTRIDE + u] = (_Float16)h;
        }
        p = q;
        __syncthreads();   // h0/h1 writes visible for next iteration's reads
    }

    // ---- epilogue: features = relu(h_last @ fcW^T + fcb) ----
    #pragma unroll
    for (int r = 0; r < 4; ++r) {
        const int row = quad * 4 + r;
        if (row < MB) h1f32[row * HID + u] = h1last[r];   // fp32 final h
    }
    __syncthreads();

    const int o = tid & 31;         // output feature 0..31
    const int r = tid >> 5;         // batch row 0..7
    float acc = fcb_lds[o];
    #pragma unroll 8
    for (int k = 0; k < HID; ++k)
        acc += h1f32[r * HID + k] * fcw_lds[o * HID + k];
    out[(bbase + r) * 32 + o] = fmaxf(acc, 0.f);
}

extern "C" void kernel_launch(void* const* d_in, const int* in_sizes, int n_in,
                              void* d_out, int out_size, void* d_ws, size_t ws_size,
                              hipStream_t stream) {
    const float* x    = (const float*)d_in[0];
    const float* Wih0 = (const float*)d_in[1];
    const float* Whh0 = (const float*)d_in[2];
    const float* bih0 = (const float*)d_in[3];
    const float* bhh0 = (const float*)d_in[4];
    const float* Wih1 = (const float*)d_in[5];
    const float* Whh1 = (const float*)d_in[6];
    const float* bih1 = (const float*)d_in[7];
    const float* bhh1 = (const float*)d_in[8];
    const float* fcW  = (const float*)d_in[9];
    const float* fcb  = (const float*)d_in[10];
    float* out = (float*)d_out;

    lstm_feat_kernel<<<2048 / MB, 256, 0, stream>>>(
        x, Wih0, Whh0, bih0, bhh0, Wih1, Whh1, bih1, bhh1, fcW, fcb, out);
}

// Round 2
// 551.856 us; speedup vs baseline: 1.0982x; 1.0982x over previous
//
#include <hip/hip_runtime.h>
#include <hip/hip_bf16.h>

// LSTMFeatureExtractor: 2-layer LSTM (H=64, IN=1, B=2048, T=512) + FC(64->32)+ReLU
// R2: (a) mirror-lane activation split: lanes quad 0/1 (real rows 0-7) compute
//     sigma(i),sigma(f); lanes quad 2/3 (mirror rows) compute tanh(g),sigma(o)
//     via uniform A*rcp(1+exp2(k*x))+B with per-lane k/A/B; 2x shfl_xor(32)
//     reassembles. Cuts wave-wide trans issues 80->48 per step.
//     (b) layer-skewed schedule: iter k computes H0[k+1] and H1[k], both from
//     prev-iteration buffers -> ONE barrier per iteration (was 2), all 24 MFMAs
//     issue at iteration top and overlap the cell math.

#define HID 64
#define TSTEPS 512
#define MB 8
#define RS 72  // f16 elems per h-row: 144B stride -> only 2-way bank alias (free)

typedef _Float16 f16x8 __attribute__((ext_vector_type(8)));
typedef float f32x4 __attribute__((ext_vector_type(4)));

#define KSIG (-1.44269504089f)   // -log2(e)
#define KTANH (2.88539008178f)   // 2*log2(e)

// main lane: gi,gf real; mirror lane: gg,go real (same cell, duplicated accs).
// slot0: main -> sigma(gi) [k=KSIG,A=1,B=0]; mirror -> tanh(gg) [k=KTANH,A=-2,B=1]
// slot1: sigma for both (gf on main, go on mirror).
__device__ __forceinline__ float cell_update(float gi, float gf, float gg, float go,
                                             float& c, bool mainl,
                                             float k0, float A0, float B0) {
    const float y0 = mainl ? gi : gg;
    const float y1 = mainl ? gf : go;
    const float s0 = A0 * __builtin_amdgcn_rcpf(1.0f + __builtin_amdgcn_exp2f(k0 * y0)) + B0;
    const float s1 = __builtin_amdgcn_rcpf(1.0f + __builtin_amdgcn_exp2f(KSIG * y1));
    const float p0 = __shfl_xor(s0, 32);   // main gets tanh(g); mirror gets sigma(i)
    const float p1 = __shfl_xor(s1, 32);   // main gets sigma(o); mirror gets sigma(f)
    const float ig = s0 * p0;              // i*g on both lanes (commutative)
    const float fv = mainl ? s1 : p1;
    const float ov = mainl ? p1 : s1;
    c = fv * c + ig;
    const float e = __builtin_amdgcn_exp2f(KTANH * c);
    const float tc = 1.0f - 2.0f * __builtin_amdgcn_rcpf(1.0f + e);
    return ov * tc;
}

__global__ __launch_bounds__(256, 1) void lstm_feat_kernel(
    const float* __restrict__ x,
    const float* __restrict__ Wih0, const float* __restrict__ Whh0,
    const float* __restrict__ bih0, const float* __restrict__ bhh0,
    const float* __restrict__ Wih1, const float* __restrict__ Whh1,
    const float* __restrict__ bih1, const float* __restrict__ bhh1,
    const float* __restrict__ fcW, const float* __restrict__ fcb,
    float* __restrict__ out)
{
    __shared__ float x_lds[TSTEPS * MB];                  // [t][row], 16 KB
    __shared__ __align__(16) _Float16 h0_lds[2][16 * RS];
    __shared__ __align__(16) _Float16 h1_lds[2][16 * RS];
    __shared__ float h1f32[MB * HID];
    __shared__ float fcw_lds[32 * HID];
    __shared__ float fcb_lds[32];

    const int tid  = threadIdx.x;
    const int wave = tid >> 6;
    const int lane = tid & 63;
    const int nq   = lane & 15;
    const int quad = lane >> 4;
    const bool mainl = quad < 2;        // rows 0-7 real; quads 2/3 mirror
    const int bbase = blockIdx.x * MB;

    // ---- one-time staging ----
    for (int i = tid; i < TSTEPS * MB; i += 256) {
        int r = i >> 9, t = i & (TSTEPS - 1);
        x_lds[t * MB + r] = x[(bbase + r) * TSTEPS + t];   // coalesced in t
    }
    for (int i = tid; i < 32 * HID; i += 256) fcw_lds[i] = fcW[i];
    if (tid < 32) fcb_lds[tid] = fcb[tid];
    for (int i = tid; i < 2 * 16 * RS; i += 256) {         // zero BOTH buffers
        ((_Float16*)h0_lds)[i] = (_Float16)0.f;
        ((_Float16*)h1_lds)[i] = (_Float16)0.f;
    }

    // ---- per-lane weight fragments (B operand) ----
    const int u = wave * 16 + nq;
    f16x8 w0[4][2], wi1[4][2], wh1[4][2];
    float b0v[4], b1v[4], wx0[4];
    #pragma unroll
    for (int g = 0; g < 4; ++g) {
        const int n = g * 64 + u;
        b0v[g] = bih0[n] + bhh0[n];
        b1v[g] = bih1[n] + bhh1[n];
        wx0[g] = Wih0[n];               // IN==1
        #pragma unroll
        for (int ks = 0; ks < 2; ++ks) {
            const int k0 = quad * 8 + ks * 32;
            f16x8 a, b, c;
            #pragma unroll
            for (int j = 0; j < 8; ++j) {
                a[j] = (_Float16)Whh0[n * HID + k0 + j];
                b[j] = (_Float16)Wih1[n * HID + k0 + j];
                c[j] = (_Float16)Whh1[n * HID + k0 + j];
            }
            w0[g][ks] = a; wi1[g][ks] = b; wh1[g][ks] = c;
        }
    }

    // per-lane activation constants for slot0
    const float k0c = mainl ? KSIG : KTANH;
    const float A0c = mainl ? 1.f : -2.f;
    const float B0c = mainl ? 0.f : 1.f;

    float c0[4] = {0.f, 0.f, 0.f, 0.f};
    float c1[4] = {0.f, 0.f, 0.f, 0.f};
    float h1last[4] = {0.f, 0.f, 0.f, 0.f};

    __syncthreads();

    // ---- skewed recurrence: iter k makes H0[k+1] (from x[k],H0[k]) and
    //      H1[k] (from H0[k],H1[k-1]); single barrier per iteration ----
    int p = 0;
    for (int k = 0; k <= TSTEPS; ++k) {
        const int q = p ^ 1;

        f16x8 a0[2], a1[2];
        a0[0] = *(const f16x8*)&h0_lds[p][nq * RS + quad * 8];
        a0[1] = *(const f16x8*)&h0_lds[p][nq * RS + quad * 8 + 32];
        a1[0] = *(const f16x8*)&h1_lds[p][nq * RS + quad * 8];
        a1[1] = *(const f16x8*)&h1_lds[p][nq * RS + quad * 8 + 32];
        const int kx = (k < TSTEPS) ? k : (TSTEPS - 1);     // k=512: dead compute
        const float4 xv = *(const float4*)&x_lds[kx * MB + (quad & 1) * 4];
        const float xr[4] = {xv.x, xv.y, xv.z, xv.w};

        // layer0 gates for t=k: b0 + x[k]*Wih0 + H0[k] @ Whh0^T
        f32x4 acc0[4], acc1[4];
        #pragma unroll
        for (int g = 0; g < 4; ++g) {
            #pragma unroll
            for (int r = 0; r < 4; ++r) acc0[g][r] = b0v[g] + xr[r] * wx0[g];
            acc0[g] = __builtin_amdgcn_mfma_f32_16x16x32_f16(a0[0], w0[g][0], acc0[g], 0, 0, 0);
            acc0[g] = __builtin_amdgcn_mfma_f32_16x16x32_f16(a0[1], w0[g][1], acc0[g], 0, 0, 0);
        }
        // layer1 gates for t=k: b1 + H0[k] @ Wih1^T + H1[k-1] @ Whh1^T
        #pragma unroll
        for (int g = 0; g < 4; ++g) {
            #pragma unroll
            for (int r = 0; r < 4; ++r) acc1[g][r] = b1v[g];
            acc1[g] = __builtin_amdgcn_mfma_f32_16x16x32_f16(a0[0], wi1[g][0], acc1[g], 0, 0, 0);
            acc1[g] = __builtin_amdgcn_mfma_f32_16x16x32_f16(a0[1], wi1[g][1], acc1[g], 0, 0, 0);
            acc1[g] = __builtin_amdgcn_mfma_f32_16x16x32_f16(a1[0], wh1[g][0], acc1[g], 0, 0, 0);
            acc1[g] = __builtin_amdgcn_mfma_f32_16x16x32_f16(a1[1], wh1[g][1], acc1[g], 0, 0, 0);
        }

        // layer0 cell update -> H0[k+1] (harmless garbage at k==512, unread)
        #pragma unroll
        for (int r = 0; r < 4; ++r) {
            const float h = cell_update(acc0[0][r], acc0[1][r], acc0[2][r], acc0[3][r],
                                        c0[r], mainl, k0c, A0c, B0c);
            h0_lds[q][(quad * 4 + r) * RS + u] = (_Float16)h;
        }
        // layer1 cell update -> H1[k]; skip k==0 (h1_lds[q] stays zero = H1[0] init)
        if (k > 0) {
            #pragma unroll
            for (int r = 0; r < 4; ++r) {
                const float h = cell_update(acc1[0][r], acc1[1][r], acc1[2][r], acc1[3][r],
                                            c1[r], mainl, k0c, A0c, B0c);
                h1last[r] = h;
                h1_lds[q][(quad * 4 + r) * RS + u] = (_Float16)h;
            }
        }
        p = q;
        __syncthreads();
    }

    // ---- epilogue: features = relu(H1[512] @ fcW^T + fcb) ----
    #pragma unroll
    for (int r = 0; r < 4; ++r) {
        const int row = quad * 4 + r;
        if (row < MB) h1f32[row * HID + u] = h1last[r];
    }
    __syncthreads();

    const int o = tid & 31;
    const int rr = tid >> 5;
    float acc = fcb_lds[o];
    #pragma unroll 8
    for (int kk = 0; kk < HID; ++kk)
        acc += h1f32[rr * HID + kk] * fcw_lds[o * HID + kk];
    out[(bbase + rr) * 32 + o] = fmaxf(acc, 0.f);
}

extern "C" void kernel_launch(void* const* d_in, const int* in_sizes, int n_in,
                              void* d_out, int out_size, void* d_ws, size_t ws_size,
                              hipStream_t stream) {
    const float* x    = (const float*)d_in[0];
    const float* Wih0 = (const float*)d_in[1];
    const float* Whh0 = (const float*)d_in[2];
    const float* bih0 = (const float*)d_in[3];
    const float* bhh0 = (const float*)d_in[4];
    const float* Wih1 = (const float*)d_in[5];
    const float* Whh1 = (const float*)d_in[6];
    const float* bih1 = (const float*)d_in[7];
    const float* bhh1 = (const float*)d_in[8];
    const float* fcW  = (const float*)d_in[9];
    const float* fcb  = (const float*)d_in[10];
    float* out = (float*)d_out;

    lstm_feat_kernel<<<2048 / MB, 256, 0, stream>>>(
        x, Wih0, Whh0, bih0, bhh0, Wih1, Whh1, bih1, bhh1, fcW, fcb, out);
}

// Round 3
// 437.106 us; speedup vs baseline: 1.3865x; 1.2625x over previous
//
#include <hip/hip_runtime.h>
#include <hip/hip_bf16.h>

// LSTMFeatureExtractor: 2-layer LSTM (H=64, IN=1, B=2048, T=512) + FC(64->32)+ReLU
// R3: MB=4, grid=512 -> 2 blocks/CU (2 waves/SIMD) for latency hiding.
//     A-row replication (read h row nq&3): every quad's D regs hold batch rows
//     0-3, so quad Q processes batch Q / all 4 gates via 3 cndmask selects.
//     Activations at the per-lane minimum: 20 wave-wide trans issues/step,
//     zero shuffles, c-state = 1 VGPR/lane, 1 LDS h-write/lane/layer.
//     RS=80 f16 (160B = 40 words = 8 mod 32) -> all b128 LDS reads <=2-way (free).

#define HID 64
#define TSTEPS 512
#define MB 4
#define RS 80

typedef _Float16 f16x8 __attribute__((ext_vector_type(8)));
typedef float f32x4 __attribute__((ext_vector_type(4)));

#define KSIG (-1.44269504089f)   // -log2(e)
#define KTANH (2.88539008178f)   // 2*log2(e)

__device__ __forceinline__ float fsig(float x) {
    return __builtin_amdgcn_rcpf(1.f + __builtin_amdgcn_exp2f(KSIG * x));
}
__device__ __forceinline__ float ftanh(float x) {
    return 1.f - 2.f * __builtin_amdgcn_rcpf(1.f + __builtin_amdgcn_exp2f(KTANH * x));
}
// pick element [quad] of a D-fragment (reg r = batch row r on every quad)
__device__ __forceinline__ float selq(f32x4 v, bool q1, bool q2) {
    const float a = q1 ? v[1] : v[0];
    const float b = q1 ? v[3] : v[2];
    return q2 ? b : a;
}

__global__ __launch_bounds__(256, 2) void lstm_feat_kernel(
    const float* __restrict__ x,
    const float* __restrict__ Wih0, const float* __restrict__ Whh0,
    const float* __restrict__ bih0, const float* __restrict__ bhh0,
    const float* __restrict__ Wih1, const float* __restrict__ Whh1,
    const float* __restrict__ bih1, const float* __restrict__ bhh1,
    const float* __restrict__ fcW, const float* __restrict__ fcb,
    float* __restrict__ out)
{
    __shared__ float x_lds[TSTEPS * MB];                   // [t][row], 8 KB
    __shared__ __align__(16) _Float16 h0_lds[2][MB * RS];  // rows 0-3 only
    __shared__ __align__(16) _Float16 h1_lds[2][MB * RS];
    __shared__ float h1f32[MB * HID];
    __shared__ float fcw_lds[32 * HID];
    __shared__ float fcb_lds[32];

    const int tid  = threadIdx.x;
    const int wave = tid >> 6;
    const int lane = tid & 63;
    const int nq   = lane & 15;
    const int quad = lane >> 4;
    const bool q1 = (quad & 1) != 0;
    const bool q2 = (quad & 2) != 0;
    const int bbase = blockIdx.x * MB;

    // ---- one-time staging ----
    for (int i = tid; i < TSTEPS * MB; i += 256) {
        int r = i >> 9, t = i & (TSTEPS - 1);
        x_lds[t * MB + r] = x[(bbase + r) * TSTEPS + t];   // coalesced in t
    }
    for (int i = tid; i < 32 * HID; i += 256) fcw_lds[i] = fcW[i];
    if (tid < 32) fcb_lds[tid] = fcb[tid];
    for (int i = tid; i < 2 * MB * RS; i += 256) {
        ((_Float16*)h0_lds)[i] = (_Float16)0.f;            // H0[0]=0, and buf1
        ((_Float16*)h1_lds)[i] = (_Float16)0.f;            // H1[0]=0, and buf1
    }

    // ---- per-lane weight fragments (B operand: lane holds W[n][k..k+8)) ----
    const int u = wave * 16 + nq;   // unit owned
    f16x8 w0[4][2], wi1[4][2], wh1[4][2];
    float b0v[4], b1v[4], wx0[4];
    #pragma unroll
    for (int g = 0; g < 4; ++g) {
        const int n = g * 64 + u;
        b0v[g] = bih0[n] + bhh0[n];
        b1v[g] = bih1[n] + bhh1[n];
        wx0[g] = Wih0[n];           // IN==1
        #pragma unroll
        for (int ks = 0; ks < 2; ++ks) {
            const int k0 = quad * 8 + ks * 32;
            f16x8 a, b, c;
            #pragma unroll
            for (int j = 0; j < 8; ++j) {
                a[j] = (_Float16)Whh0[n * HID + k0 + j];
                b[j] = (_Float16)Wih1[n * HID + k0 + j];
                c[j] = (_Float16)Whh1[n * HID + k0 + j];
            }
            w0[g][ks] = a; wi1[g][ks] = b; wh1[g][ks] = c;
        }
    }

    const f32x4 zero4 = {0.f, 0.f, 0.f, 0.f};
    const int arow = (nq & 3) * RS + quad * 8;   // A-replicated read offset
    float c0 = 0.f, c1 = 0.f;

    __syncthreads();

    // ---- skewed recurrence: iter k makes H0[k+1] (x[k],H0[k]) and H1[k]
    //      (H0[k],H1[k-1]); single barrier; 512 even iterations ----
    int p = 0;
    for (int k = 0; k < TSTEPS; ++k) {
        const int q = p ^ 1;

        f16x8 a0[2], a1[2];
        a0[0] = *(const f16x8*)&h0_lds[p][arow];
        a0[1] = *(const f16x8*)&h0_lds[p][arow + 32];
        a1[0] = *(const f16x8*)&h1_lds[p][arow];
        a1[1] = *(const f16x8*)&h1_lds[p][arow + 32];
        const float xq = x_lds[k * MB + quad];   // this lane's batch row = quad

        f32x4 acc0[4], acc1[4];
        #pragma unroll
        for (int g = 0; g < 4; ++g) {
            acc0[g] = __builtin_amdgcn_mfma_f32_16x16x32_f16(a0[0], w0[g][0], zero4, 0, 0, 0);
            acc0[g] = __builtin_amdgcn_mfma_f32_16x16x32_f16(a0[1], w0[g][1], acc0[g], 0, 0, 0);
        }
        #pragma unroll
        for (int g = 0; g < 4; ++g) {
            acc1[g] = __builtin_amdgcn_mfma_f32_16x16x32_f16(a0[0], wi1[g][0], zero4, 0, 0, 0);
            acc1[g] = __builtin_amdgcn_mfma_f32_16x16x32_f16(a0[1], wi1[g][1], acc1[g], 0, 0, 0);
            acc1[g] = __builtin_amdgcn_mfma_f32_16x16x32_f16(a1[0], wh1[g][0], acc1[g], 0, 0, 0);
            acc1[g] = __builtin_amdgcn_mfma_f32_16x16x32_f16(a1[1], wh1[g][1], acc1[g], 0, 0, 0);
        }

        // layer0 cell for batch row = quad (reg index quad via selects)
        {
            const float pi = selq(acc0[0], q1, q2) + b0v[0] + xq * wx0[0];
            const float pf = selq(acc0[1], q1, q2) + b0v[1] + xq * wx0[1];
            const float pg = selq(acc0[2], q1, q2) + b0v[2] + xq * wx0[2];
            const float po = selq(acc0[3], q1, q2) + b0v[3] + xq * wx0[3];
            const float iv = fsig(pi), fv = fsig(pf), gv = ftanh(pg), ov = fsig(po);
            c0 = fv * c0 + iv * gv;
            h0_lds[q][quad * RS + u] = (_Float16)(ov * ftanh(c0));
        }
        // layer1 cell -> H1[k]; skip k==0 (buffers pre-zeroed = H1[0])
        if (k > 0) {
            const float pi = selq(acc1[0], q1, q2) + b1v[0];
            const float pf = selq(acc1[1], q1, q2) + b1v[1];
            const float pg = selq(acc1[2], q1, q2) + b1v[2];
            const float po = selq(acc1[3], q1, q2) + b1v[3];
            const float iv = fsig(pi), fv = fsig(pf), gv = ftanh(pg), ov = fsig(po);
            c1 = fv * c1 + iv * gv;
            h1_lds[q][quad * RS + u] = (_Float16)(ov * ftanh(c1));
        }
        p = q;
        __syncthreads();
    }

    // ---- peeled final layer-1 step: H1[512] from H0[512], H1[511] ----
    float h1last;
    {
        f16x8 a0f[2], a1f[2];
        a0f[0] = *(const f16x8*)&h0_lds[p][arow];
        a0f[1] = *(const f16x8*)&h0_lds[p][arow + 32];
        a1f[0] = *(const f16x8*)&h1_lds[p][arow];
        a1f[1] = *(const f16x8*)&h1_lds[p][arow + 32];
        f32x4 acc1[4];
        #pragma unroll
        for (int g = 0; g < 4; ++g) {
            acc1[g] = __builtin_amdgcn_mfma_f32_16x16x32_f16(a0f[0], wi1[g][0], zero4, 0, 0, 0);
            acc1[g] = __builtin_amdgcn_mfma_f32_16x16x32_f16(a0f[1], wi1[g][1], acc1[g], 0, 0, 0);
            acc1[g] = __builtin_amdgcn_mfma_f32_16x16x32_f16(a1f[0], wh1[g][0], acc1[g], 0, 0, 0);
            acc1[g] = __builtin_amdgcn_mfma_f32_16x16x32_f16(a1f[1], wh1[g][1], acc1[g], 0, 0, 0);
        }
        const float pi = selq(acc1[0], q1, q2) + b1v[0];
        const float pf = selq(acc1[1], q1, q2) + b1v[1];
        const float pg = selq(acc1[2], q1, q2) + b1v[2];
        const float po = selq(acc1[3], q1, q2) + b1v[3];
        const float iv = fsig(pi), fv = fsig(pf), gv = ftanh(pg), ov = fsig(po);
        c1 = fv * c1 + iv * gv;
        h1last = ov * ftanh(c1);
    }

    // ---- epilogue: features = relu(H1[512] @ fcW^T + fcb) ----
    h1f32[quad * HID + u] = h1last;   // each lane: 1 value (row=quad, unit=u)
    __syncthreads();

    if (tid < MB * 32) {
        const int o  = tid & 31;
        const int rr = tid >> 5;
        float acc = fcb_lds[o];
        #pragma unroll 8
        for (int kk = 0; kk < HID; ++kk)
            acc += h1f32[rr * HID + kk] * fcw_lds[o * HID + kk];
        out[(bbase + rr) * 32 + o] = fmaxf(acc, 0.f);
    }
}

extern "C" void kernel_launch(void* const* d_in, const int* in_sizes, int n_in,
                              void* d_out, int out_size, void* d_ws, size_t ws_size,
                              hipStream_t stream) {
    const float* x    = (const float*)d_in[0];
    const float* Wih0 = (const float*)d_in[1];
    const float* Whh0 = (const float*)d_in[2];
    const float* bih0 = (const float*)d_in[3];
    const float* bhh0 = (const float*)d_in[4];
    const float* Wih1 = (const float*)d_in[5];
    const float* Whh1 = (const float*)d_in[6];
    const float* bih1 = (const float*)d_in[7];
    const float* bhh1 = (const float*)d_in[8];
    const float* fcW  = (const float*)d_in[9];
    const float* fcb  = (const float*)d_in[10];
    float* out = (float*)d_out;

    lstm_feat_kernel<<<2048 / MB, 256, 0, stream>>>(
        x, Wih0, Whh0, bih0, bhh0, Wih1, Whh1, bih1, bhh1, fcW, fcb, out);
}